// Round 2
// baseline (58666.010 us; speedup 1.0000x reference)
//
#include <hip/hip_runtime.h>
#include <math.h>

#define NPTS  2048
#define DIM   96
#define NSTEP (NPTS / 64)   // 32 elements per lane in the single-wave kernel

// Device-global state: rewritten in full every call (deterministic).
__device__ double g_xd[NPTS * DIM];
__device__ double g_sq[NPTS];
__device__ double g_d2[(size_t)NPTS * NPTS];   // 32 MB fp64 distance matrix
__device__ double g_rowmin[NPTS];
__device__ int    g_rowarg[NPTS];

// ---------------------------------------------------------------- prep ----
__global__ void prep_kernel(const float* __restrict__ x) {
    int r = blockIdx.x;
    int t = threadIdx.x;
    __shared__ double s[DIM];
    if (t < DIM) {
        double v = (double)x[r * DIM + t];
        g_xd[r * DIM + t] = v;
        s[t] = v * v;
    }
    __syncthreads();
    if (t == 0) {
        double acc = 0.0;
        for (int d = 0; d < DIM; ++d) acc += s[d];
        g_sq[r] = acc;
    }
}

// ---------------------------------------------------------------- dist ----
__global__ void dist_kernel() {
    int c = blockIdx.x * blockDim.x + threadIdx.x;
    int r = blockIdx.y * blockDim.y + threadIdx.y;
    const double* __restrict__ xr = &g_xd[r * DIM];
    const double* __restrict__ xc = &g_xd[c * DIM];
    double acc = 0.0;
#pragma unroll 8
    for (int d = 0; d < DIM; ++d) acc += xr[d] * xc[d];
    double v = g_sq[r] + g_sq[c] - 2.0 * acc;
    if (v < 0.0) v = 0.0;
    if (r == c) v = (double)INFINITY;
    g_d2[(size_t)r * NPTS + c] = v;
}

// -------------------------------------------------------------- rowmin ----
// Per-row (min, argmin) over c != r, smallest-column tie-break.
__global__ void rowmin_kernel() {
    int r = blockIdx.x;
    int t = threadIdx.x;
    double bv = (double)INFINITY;
    int    bi = NPTS;
    const double* __restrict__ row = &g_d2[(size_t)r * NPTS];
    for (int c = t; c < NPTS; c += 256) {
        if (c == r) continue;
        double v = row[c];
        if (v < bv) { bv = v; bi = c; }
    }
    for (int off = 32; off >= 1; off >>= 1) {
        double ov = __shfl_down(bv, off);
        int    oi = __shfl_down(bi, off);
        if (ov < bv || (ov == bv && oi < bi)) { bv = ov; bi = oi; }
    }
    __shared__ double sv[4];
    __shared__ int    si[4];
    int wid = t >> 6;
    if ((t & 63) == 0) { sv[wid] = bv; si[wid] = bi; }
    __syncthreads();
    if (t == 0) {
        for (int w = 1; w < 4; ++w)
            if (sv[w] < bv || (sv[w] == bv && si[w] < bi)) { bv = sv[w]; bi = si[w]; }
        g_rowmin[r] = bv;
        g_rowarg[r] = bi;
    }
}

// ---------------------------------------------------------------- ward ----
// Single-wave (64 lanes, lock-step): ZERO __syncthreads, all reductions are
// shuffle butterflies, ~2 vmcnt waits per merge instead of ~14 barrier drains.
__device__ inline void wave_argmin(double& v, int& idx) {
#pragma unroll
    for (int m = 1; m < 64; m <<= 1) {
        double ov = __shfl_xor(v, m);
        int    oi = __shfl_xor(idx, m);
        if (ov < v || (ov == v && oi < idx)) { v = ov; idx = oi; }
    }
    // lexicographic min is associative+commutative: all lanes converge.
}

__global__ void __launch_bounds__(64, 1) ward_kernel(const int* __restrict__ kptr,
                                                     float* __restrict__ out) {
    __shared__ double         s_rowmin[NPTS];   // 16 KB
    __shared__ double         s_newrow[NPTS];   // 16 KB (fresh row i stash)
    __shared__ int            s_sizes[NPTS];    //  8 KB (exact integer sizes)
    __shared__ unsigned short s_rowarg[NPTS];   //  4 KB
    __shared__ unsigned short s_cluster[NPTS];  //  4 KB
    __shared__ unsigned short s_rescan[NPTS];   //  4 KB (reused as labels at end)
    __shared__ unsigned char  s_active[NPTS];   //  2 KB
    __shared__ int            s_nres;

    const int t = threadIdx.x;   // 0..63
    const int k = *kptr;

#pragma unroll
    for (int s = 0; s < NSTEP; ++s) {
        int p = t + (s << 6);
        s_rowmin[p]  = g_rowmin[p];
        s_rowarg[p]  = (unsigned short)g_rowarg[p];
        s_sizes[p]   = 1;
        s_active[p]  = 1;
        s_cluster[p] = (unsigned short)p;
    }
    if (t == 0) s_nres = 0;

    const int nmerge = NPTS - k;
    for (int it = 0; it < nmerge; ++it) {
        // previous iteration's global stores must be visible to this one's loads
        asm volatile("s_waitcnt vmcnt(0)" ::: "memory");

        // ---- 1. global argmin over row minima (ties: smallest row) ----
        double bv = (double)INFINITY;
        int    bi = NPTS;
#pragma unroll
        for (int s = 0; s < NSTEP; ++s) {
            int r = t + (s << 6);
            double v = s_rowmin[r];           // inactive rows hold +inf
            if (v < bv) { bv = v; bi = r; }   // ascending r + strict < => smallest row
        }
        wave_argmin(bv, bi);
        const int    i   = bi;
        const int    j   = (int)s_rowarg[i];  // j > i (else row j would have won)
        const double dij = bv;
        const double si  = (double)s_sizes[i];
        const double sj  = (double)s_sizes[j];
        if (t == 0) {
            s_sizes[i] += s_sizes[j];
            s_active[j] = 0;
            s_rowmin[j] = (double)INFINITY;
            s_nres      = 0;
        }
        const size_t rowi = (size_t)i * NPTS;
        const size_t rowj = (size_t)j * NPTS;

        // ---- 2. Lance-Williams update: hoist ALL 64 row loads first ----
        double av[NSTEP], bw[NSTEP];
#pragma unroll
        for (int s = 0; s < NSTEP; ++s) {
            int m = t + (s << 6);
            av[s] = g_d2[rowi + m];
            bw[s] = g_d2[rowj + m];
        }
#pragma unroll
        for (int s = 0; s < NSTEP; ++s) {
            int m = t + (s << 6);
            if ((int)s_cluster[m] == j) s_cluster[m] = (unsigned short)i;
            bool act = (s_active[m] != 0) && (m != i) && (m != j);
            double sm = (double)s_sizes[m];
            double nd = ((si + sm) * av[s] + (sj + sm) * bw[s] - sm * dij)
                        / (si + sj + sm);
            if (act) {
                g_d2[rowi + m]             = nd;   // row write (coalesced)
                g_d2[(size_t)m * NPTS + i] = nd;   // column write (scattered)
                s_newrow[m] = nd;
                int am = (int)s_rowarg[m];
                if (am == i || am == j) {
                    int slot = atomicAdd(&s_nres, 1);   // min location invalidated
                    s_rescan[slot] = (unsigned short)m;
                } else if (nd < s_rowmin[m] ||
                           (nd == s_rowmin[m] && i < am)) {
                    s_rowmin[m] = nd;
                    s_rowarg[m] = (unsigned short)i;
                }
            } else {
                s_newrow[m] = (double)INFINITY;
            }
        }

        // ---- 3. rescan merged row i entirely from LDS stash ----
        {
            double rv = (double)INFINITY;
            int    ri = NPTS;
#pragma unroll
            for (int s = 0; s < NSTEP; ++s) {
                int c = t + (s << 6);
                double v = s_newrow[c];       // inf at i, j, inactive
                if (v < rv) { rv = v; ri = c; }
            }
            wave_argmin(rv, ri);
            if (t == 0) { s_rowmin[i] = rv; s_rowarg[i] = (unsigned short)ri; }
        }

        // ---- 4. full rescans for rows whose argmin pointed at i or j ----
        int nres = s_nres;                    // LDS read, same wave: ordered
        for (int q = 0; q < nres; ++q) {
            int    r    = (int)s_rescan[q];
            size_t rowr = (size_t)r * NPTS;
            double vv[NSTEP];
#pragma unroll
            for (int s = 0; s < NSTEP; ++s)
                vv[s] = g_d2[rowr + t + (s << 6)];
            double rv = (double)INFINITY;
            int    ri = NPTS;
#pragma unroll
            for (int s = 0; s < NSTEP; ++s) {
                int c = t + (s << 6);
                double v = (c == i) ? s_newrow[r] : vv[s];  // col-i write in flight
                if ((s_active[c] != 0) && (c != r) &&
                    (v < rv || (v == rv && c < ri))) { rv = v; ri = c; }
            }
            wave_argmin(rv, ri);
            if (t == 0) { s_rowmin[r] = rv; s_rowarg[r] = (unsigned short)ri; }
        }
    }

    // ---- labels: rank of surviving representative (= min point index) ----
    {
        int base = t << 5;                    // 32 rows per lane
        int cnt  = 0;
        for (int r2 = 0; r2 < 32; ++r2) cnt += s_active[base + r2];
        int v = cnt;                          // inclusive scan across lanes
#pragma unroll
        for (int off = 1; off < 64; off <<= 1) {
            int o = __shfl_up(v, off);
            if (t >= off) v += o;
        }
        int run = v - cnt;                    // exclusive prefix for this chunk
        for (int r2 = 0; r2 < 32; ++r2) {
            int r = base + r2;
            s_rescan[r] = (unsigned short)run;   // reuse as label table
            run += s_active[r];
        }
    }
#pragma unroll
    for (int s = 0; s < NSTEP; ++s) {
        int p   = t + (s << 6);
        int lbl = (int)s_rescan[(int)s_cluster[p]];
        out[(size_t)p * k + lbl] = 1.0f;      // out pre-zeroed via hipMemsetAsync
    }
}

// -------------------------------------------------------------- launch ----
extern "C" void kernel_launch(void* const* d_in, const int* in_sizes, int n_in,
                              void* d_out, int out_size, void* d_ws, size_t ws_size,
                              hipStream_t stream) {
    const float* x    = (const float*)d_in[0];
    const int*   kptr = (const int*)d_in[1];
    float*       out  = (float*)d_out;

    hipMemsetAsync(d_out, 0, (size_t)out_size * sizeof(float), stream);

    prep_kernel<<<NPTS, 128, 0, stream>>>(x);
    dist_kernel<<<dim3(NPTS / 16, NPTS / 16), dim3(16, 16), 0, stream>>>();
    rowmin_kernel<<<NPTS, 256, 0, stream>>>();
    ward_kernel<<<1, 64, 0, stream>>>(kptr, out);
}

// Round 5
// 3516.056 us; speedup vs baseline: 16.6852x; 16.6852x over previous
//
#include <hip/hip_runtime.h>
#include <math.h>

#define NPTS   2048
#define DIM    96
#define PITCH  2048
#define TB     8
#define ROUNDS 48

// ---- fixed-slot state: slot index == cluster representative (min point) ----
__device__ double g_cent[DIM * PITCH];   // transposed centroids, updated in place
__device__ double g_sz[NPTS];
__device__ double g_nrm[NPTS];           // ||mu||^2
__device__ int    g_act[NPTS];
__device__ double g_nnv[NPTS];
__device__ int    g_nni[NPTS];           // -1 for killed slots
__device__ int    g_reci[NPTS];          // merge records: keeper (smaller slot)
__device__ int    g_recj[NPTS];          //                killed (larger slot)
__device__ double g_rech[NPTS];          //                Ward height
__device__ int    g_a, g_done, g_mcount;

// ---------------------------------------------------------------- init ----
__global__ void init_kernel(const float* __restrict__ x) {
    int p = blockIdx.x * 256 + threadIdx.x;   // grid 8 x 256
    if (p < NPTS) {
        double nr = 0.0;
        for (int d = 0; d < DIM; ++d) {
            double v = (double)x[p * DIM + d];
            g_cent[d * PITCH + p] = v;
            nr += v * v;
        }
        g_nrm[p] = nr; g_sz[p] = 1.0; g_act[p] = 1;
        g_nni[p] = -1; g_nnv[p] = (double)INFINITY;
        g_reci[p] = 0; g_recj[p] = 0; g_rech[p] = (double)INFINITY;
    }
    if (p == 0) { g_a = NPTS; g_done = 0; g_mcount = 0; }
}

// -------------------------------------------------------------- nn_pass ----
// For each ACTIVE slot b: (nnv,nni) = lexicographic argmin over active m != b of
// D(b,m) = 2*(sb*sm/(sb+sm)) * (nb + nm - 2*dot).  Bit-symmetric in (b,m):
// commutative ops, identical d-order => global-min pair is always mutual.
__global__ void __launch_bounds__(512) nn_pass() {
    if (g_done) return;
    const int tile0 = blockIdx.x * TB;
    const int t = threadIdx.x;

    __shared__ int    sAct[TB];
    __shared__ double sMu[DIM * TB];          // 6 KB row-centroid tile
    __shared__ double sNb[TB], sSb[TB];
    __shared__ double sRedV[8 * TB];
    __shared__ int    sRedI[8 * TB];

    if (t < TB) {
        sAct[t] = g_act[tile0 + t];
        sNb[t]  = g_nrm[tile0 + t];
        sSb[t]  = g_sz[tile0 + t];
    }
    __syncthreads();
    int anyact = 0;
#pragma unroll
    for (int bi = 0; bi < TB; ++bi) anyact |= sAct[bi];
    if (!anyact) return;

    for (int e = t; e < DIM * TB; e += 512)
        sMu[e] = g_cent[(e >> 3) * PITCH + tile0 + (e & 7)];
    __syncthreads();

    // thread t handles candidates m = t, t+512, t+1024, t+1536 (always in range)
    double acc[4][TB];
#pragma unroll
    for (int q = 0; q < 4; ++q)
#pragma unroll
        for (int bi = 0; bi < TB; ++bi) acc[q][bi] = 0.0;

    for (int d = 0; d < DIM; ++d) {
        double mu[TB];
#pragma unroll
        for (int bi = 0; bi < TB; ++bi) mu[bi] = sMu[d * TB + bi];
        double x0 = g_cent[d * PITCH + t];
        double x1 = g_cent[d * PITCH + t + 512];
        double x2 = g_cent[d * PITCH + t + 1024];
        double x3 = g_cent[d * PITCH + t + 1536];
#pragma unroll
        for (int bi = 0; bi < TB; ++bi) {
            acc[0][bi] += mu[bi] * x0;
            acc[1][bi] += mu[bi] * x1;
            acc[2][bi] += mu[bi] * x2;
            acc[3][bi] += mu[bi] * x3;
        }
    }

    double bv[TB]; int bidx[TB];
#pragma unroll
    for (int bi = 0; bi < TB; ++bi) { bv[bi] = (double)INFINITY; bidx[bi] = 0x7FFFFFFF; }
#pragma unroll
    for (int q = 0; q < 4; ++q) {
        int m  = t + q * 512;
        int am = g_act[m];
        double sm = g_sz[m], nm = g_nrm[m];
#pragma unroll
        for (int bi = 0; bi < TB; ++bi) {
            int bcol = tile0 + bi;
            double f = (sSb[bi] * sm) / (sSb[bi] + sm);
            double D = (2.0 * f) * ((sNb[bi] + nm) - 2.0 * acc[q][bi]);
            // within-thread m ascending + strict < keeps smallest m on ties
            if (am && m != bcol && D < bv[bi]) { bv[bi] = D; bidx[bi] = m; }
        }
    }

    const int lane = t & 63, w = t >> 6;
#pragma unroll
    for (int bi = 0; bi < TB; ++bi) {
        double v = bv[bi]; int ix = bidx[bi];
        for (int off = 1; off < 64; off <<= 1) {
            double ov = __shfl_xor(v, off);
            int    oi = __shfl_xor(ix, off);
            if (ov < v || (ov == v && oi < ix)) { v = ov; ix = oi; }
        }
        if (lane == 0) { sRedV[w * TB + bi] = v; sRedI[w * TB + bi] = ix; }
    }
    __syncthreads();
    if (t < TB && sAct[t]) {
        double v = sRedV[t]; int ix = sRedI[t];
        for (int w2 = 1; w2 < 8; ++w2) {
            double ov = sRedV[w2 * TB + t]; int oi = sRedI[w2 * TB + t];
            if (ov < v || (ov == v && oi < ix)) { v = ov; ix = oi; }
        }
        g_nnv[tile0 + t] = v;
        g_nni[tile0 + t] = ix;
    }
}

// ----------------------------------------------------------- merge_pass ----
// Merge ALL mutual pairs (disjoint => one thread owns one merge). Runs until
// the FULL dendrogram is built (a == 1) — required so the height-sort
// selection sees every one of the n-k smallest merges.
__global__ void __launch_bounds__(1024) merge_pass() {
    if (g_done) return;
    __shared__ int sNp;
    const int t = threadIdx.x;
    if (t == 0) sNp = 0;
    __syncthreads();
    for (int b = t; b < NPTS; b += 1024) {
        int j = g_nni[b];
        if (j > b && j < NPTS && g_nni[j] == b) {   // mutual pair, b = keeper
            int r = atomicAdd(&g_mcount, 1);
            g_reci[r] = b; g_recj[r] = j; g_rech[r] = g_nnv[b];
            double sb = g_sz[b], sj = g_sz[j], s2 = sb + sj;
            double nr = 0.0;
            for (int d = 0; d < DIM; ++d) {
                double v = (sb * g_cent[d * PITCH + b] + sj * g_cent[d * PITCH + j]) / s2;
                g_cent[d * PITCH + b] = v;
                nr += v * v;
            }
            g_sz[b] = s2; g_nrm[b] = nr;
            g_act[j] = 0; g_nni[j] = -1; g_nnv[j] = (double)INFINITY;
            atomicAdd(&sNp, 1);
        }
    }
    __syncthreads();
    if (t == 0) {
        g_a -= sNp;
        g_done = (g_a <= 1) ? 1 : 0;
    }
}

// ------------------------------------------------------------- finisher ----
__global__ void __launch_bounds__(1024) finisher(const int* __restrict__ kptr,
                                                 float* __restrict__ out) {
    __shared__ double D0[NPTS];   // 16 KB: nnv / sort keys
    __shared__ int    I0[NPTS];   //  8 KB: nni / sort payload
    __shared__ int    I1[NPTS];   //  8 KB: parent ping
    __shared__ int    I2[NPTS];   //  8 KB: parent pong
    __shared__ int    I3[NPTS];   //  8 KB: rank ping
    __shared__ int    I4[NPTS];   //  8 KB: rank pong
    __shared__ int    sNp;

    const int t = threadIdx.x, lane = t & 63, w = t >> 6;
    const int k = *kptr;
    int a = g_a;

    // ---- phase 2: in-block mutual-NN safety net until FULL dendrogram ----
    for (int guard = 0; guard < NPTS && a > 1; ++guard) {
        for (int b = w; b < NPTS; b += 16) {          // wave w owns slot b
            if (!g_act[b]) { if (lane == 0) { D0[b] = (double)INFINITY; I0[b] = -1; } continue; }
            double sb = g_sz[b], nb = g_nrm[b];
            double bvv = (double)INFINITY; int bii = 0x7FFFFFFF;
            for (int m = lane; m < NPTS; m += 64) {
                if (!g_act[m] || m == b) continue;
                double dot = 0.0;
                for (int d = 0; d < DIM; ++d)
                    dot += g_cent[d * PITCH + b] * g_cent[d * PITCH + m];
                double sm = g_sz[m], nm = g_nrm[m];
                double f = (sb * sm) / (sb + sm);
                double D = (2.0 * f) * ((nb + nm) - 2.0 * dot);
                if (D < bvv || (D == bvv && m < bii)) { bvv = D; bii = m; }
            }
            for (int off = 1; off < 64; off <<= 1) {
                double ov = __shfl_xor(bvv, off);
                int    oi = __shfl_xor(bii, off);
                if (ov < bvv || (ov == bvv && oi < bii)) { bvv = ov; bii = oi; }
            }
            if (lane == 0) { D0[b] = bvv; I0[b] = bii; }
        }
        __syncthreads();
        if (t == 0) sNp = 0;
        __syncthreads();
        for (int b = t; b < NPTS; b += 1024) {
            int j = I0[b];
            if (j > b && j < NPTS && I0[j] == b) {
                int r = atomicAdd(&g_mcount, 1);
                g_reci[r] = b; g_recj[r] = j; g_rech[r] = D0[b];
                double sb = g_sz[b], sj = g_sz[j], s2 = sb + sj;
                double nr = 0.0;
                for (int d = 0; d < DIM; ++d) {
                    double v = (sb * g_cent[d * PITCH + b] + sj * g_cent[d * PITCH + j]) / s2;
                    g_cent[d * PITCH + b] = v; nr += v * v;
                }
                g_sz[b] = s2; g_nrm[b] = nr; g_act[j] = 0;
                atomicAdd(&sNp, 1);
            }
        }
        __syncthreads();
        a -= sNp;
        __syncthreads();
    }

    // ---- phase 3: sort ALL 2047 heights, apply the n-k smallest, rank, scatter ----
    const int M    = g_mcount;
    const int nsel = NPTS - k;
    __syncthreads();
    for (int e = t; e < NPTS; e += 1024) {
        D0[e] = (e < M) ? g_rech[e] : (double)INFINITY;
        I0[e] = e;
    }
    __syncthreads();
    for (int k2 = 2; k2 <= NPTS; k2 <<= 1) {
        for (int j2 = k2 >> 1; j2 > 0; j2 >>= 1) {
            for (int i = t; i < NPTS; i += 1024) {
                int ixj = i ^ j2;
                if (ixj > i) {
                    bool up = ((i & k2) == 0);
                    double a0 = D0[i], a1 = D0[ixj];
                    if (up ? (a0 > a1) : (a0 < a1)) {
                        D0[i] = a1; D0[ixj] = a0;
                        int ti_ = I0[i]; I0[i] = I0[ixj]; I0[ixj] = ti_;
                    }
                }
            }
            __syncthreads();
        }
    }
    for (int p = t; p < NPTS; p += 1024) I1[p] = p;
    __syncthreads();
    for (int r = t; r < nsel; r += 1024) {
        int rec = I0[r];
        I1[g_recj[rec]] = g_reci[rec];   // each killed slot appears exactly once
    }
    __syncthreads();
    int* psrc = I1; int* pdst = I2;
    for (int it2 = 0; it2 < 11; ++it2) {          // 2^11 >= max chain depth
        for (int p = t; p < NPTS; p += 1024) pdst[p] = psrc[psrc[p]];
        __syncthreads();
        int* tp = psrc; psrc = pdst; pdst = tp;
    }
    for (int p = t; p < NPTS; p += 1024) I3[p] = (psrc[p] == p) ? 1 : 0;
    __syncthreads();
    int* rsrc = I3; int* rdst = I4;
    for (int off = 1; off < NPTS; off <<= 1) {
        for (int p = t; p < NPTS; p += 1024)
            rdst[p] = rsrc[p] + ((p >= off) ? rsrc[p - off] : 0);
        __syncthreads();
        int* tp = rsrc; rsrc = rdst; rdst = tp;
    }
    for (int p = t; p < NPTS; p += 1024) {
        int lbl = rsrc[psrc[p]] - 1;              // rank of root, ascending
        out[(size_t)p * k + lbl] = 1.0f;          // out pre-zeroed
    }
}

// -------------------------------------------------------------- launch ----
extern "C" void kernel_launch(void* const* d_in, const int* in_sizes, int n_in,
                              void* d_out, int out_size, void* d_ws, size_t ws_size,
                              hipStream_t stream) {
    const float* x    = (const float*)d_in[0];
    const int*   kptr = (const int*)d_in[1];
    float*       out  = (float*)d_out;

    hipMemsetAsync(d_out, 0, (size_t)out_size * sizeof(float), stream);
    init_kernel<<<8, 256, 0, stream>>>(x);
    for (int r = 0; r < ROUNDS; ++r) {
        nn_pass<<<NPTS / TB, 512, 0, stream>>>();
        merge_pass<<<1, 1024, 0, stream>>>();
    }
    finisher<<<1, 1024, 0, stream>>>(kptr, out);
}

// Round 6
// 3474.892 us; speedup vs baseline: 16.8828x; 1.0118x over previous
//
#include <hip/hip_runtime.h>
#include <math.h>

#define NPTS   2048
#define DIM    96
#define PITCH  2048
#define TB     8
#define ROUNDS 48

// ---- fixed-slot state: slot index == cluster representative (min point) ----
// g_cidx is a VIEW (ascending list of active slots) — slots are never renamed.
__device__ double g_cent[DIM * PITCH];   // transposed centroids, updated in place
__device__ double g_sz[NPTS];
__device__ double g_nrm[NPTS];           // ||mu||^2
__device__ int    g_act[NPTS];
__device__ int    g_cidx[NPTS];          // compacted active slot ids, ascending
__device__ double g_nnv[NPTS];
__device__ int    g_nni[NPTS];           // -1 for killed slots
__device__ int    g_reci[NPTS];          // merge records: keeper (smaller slot)
__device__ int    g_recj[NPTS];          //                killed (larger slot)
__device__ double g_rech[NPTS];          //                Ward height
__device__ int    g_a, g_done, g_mcount;

// ---------------------------------------------------------------- init ----
__global__ void init_kernel(const float* __restrict__ x) {
    int p = blockIdx.x * 256 + threadIdx.x;   // grid 8 x 256
    if (p < NPTS) {
        double nr = 0.0;
        for (int d = 0; d < DIM; ++d) {
            double v = (double)x[p * DIM + d];
            g_cent[d * PITCH + p] = v;
            nr += v * v;
        }
        g_nrm[p] = nr; g_sz[p] = 1.0; g_act[p] = 1; g_cidx[p] = p;
        g_nni[p] = -1; g_nnv[p] = (double)INFINITY;
        g_reci[p] = 0; g_recj[p] = 0; g_rech[p] = (double)INFINITY;
    }
    if (p == 0) { g_a = NPTS; g_done = 0; g_mcount = 0; }
}

// -------------------------------------------------------------- nn_pass ----
// Compacted: block handles 8 compacted rows, candidates loop m < a via g_cidx.
// D(b,m) = 2*(sb*sm/(sb+sm)) * (nb + nm - 2*dot) — bit-symmetric in (b,m).
// Compact ascending == original ascending, so tie-breaks match R5 exactly.
__global__ void __launch_bounds__(512) nn_pass() {
    if (g_done) return;
    const int a = g_a;
    const int tile0 = blockIdx.x * TB;
    if (tile0 >= a) return;
    const int t = threadIdx.x;

    __shared__ int    sIdx[TB];
    __shared__ double sMu[DIM * TB];          // 6 KB row-centroid tile
    __shared__ double sNb[TB], sSb[TB];
    __shared__ double sRedV[8 * TB];
    __shared__ int    sRedI[8 * TB];

    if (t < TB) {
        int cm   = tile0 + t;
        int orig = (cm < a) ? g_cidx[cm] : -1;
        sIdx[t] = orig;
        sNb[t]  = (orig >= 0) ? g_nrm[orig] : 0.0;
        sSb[t]  = (orig >= 0) ? g_sz[orig]  : 1.0;
    }
    __syncthreads();
    for (int e = t; e < DIM * TB; e += 512) {
        int col = sIdx[e & 7];
        sMu[e] = (col >= 0) ? g_cent[(e >> 3) * PITCH + col] : 0.0;
    }
    __syncthreads();

    // thread t handles compacted candidates m = t + q*512, q = 0..3
    int om[4]; bool vld[4];
#pragma unroll
    for (int q = 0; q < 4; ++q) {
        int m  = t + q * 512;
        vld[q] = (m < a);
        om[q]  = g_cidx[vld[q] ? m : (a - 1)];   // clamped safe gather
    }

    double acc[4][TB];
#pragma unroll
    for (int q = 0; q < 4; ++q)
#pragma unroll
        for (int bi = 0; bi < TB; ++bi) acc[q][bi] = 0.0;

    for (int d = 0; d < DIM; ++d) {
        double mu[TB];
#pragma unroll
        for (int bi = 0; bi < TB; ++bi) mu[bi] = sMu[d * TB + bi];
        double x0 = g_cent[d * PITCH + om[0]];
        double x1 = g_cent[d * PITCH + om[1]];
        double x2 = g_cent[d * PITCH + om[2]];
        double x3 = g_cent[d * PITCH + om[3]];
#pragma unroll
        for (int bi = 0; bi < TB; ++bi) {
            acc[0][bi] += mu[bi] * x0;
            acc[1][bi] += mu[bi] * x1;
            acc[2][bi] += mu[bi] * x2;
            acc[3][bi] += mu[bi] * x3;
        }
    }

    double bv[TB]; int bidx[TB];
#pragma unroll
    for (int bi = 0; bi < TB; ++bi) { bv[bi] = (double)INFINITY; bidx[bi] = 0x7FFFFFFF; }
#pragma unroll
    for (int q = 0; q < 4; ++q) {
        if (!vld[q]) continue;
        int    cm = t + q * 512;
        double sm = g_sz[om[q]], nm = g_nrm[om[q]];
#pragma unroll
        for (int bi = 0; bi < TB; ++bi) {
            double f = (sSb[bi] * sm) / (sSb[bi] + sm);
            double D = (2.0 * f) * ((sNb[bi] + nm) - 2.0 * acc[q][bi]);
            // within-thread m ascending + strict < keeps smallest id on ties
            if (cm != tile0 + bi && D < bv[bi]) { bv[bi] = D; bidx[bi] = om[q]; }
        }
    }

    const int lane = t & 63, w = t >> 6;
#pragma unroll
    for (int bi = 0; bi < TB; ++bi) {
        double v = bv[bi]; int ix = bidx[bi];
        for (int off = 1; off < 64; off <<= 1) {
            double ov = __shfl_xor(v, off);
            int    oi = __shfl_xor(ix, off);
            if (ov < v || (ov == v && oi < ix)) { v = ov; ix = oi; }
        }
        if (lane == 0) { sRedV[w * TB + bi] = v; sRedI[w * TB + bi] = ix; }
    }
    __syncthreads();
    if (t < TB && tile0 + t < a) {
        double v = sRedV[t]; int ix = sRedI[t];
        for (int w2 = 1; w2 < 8; ++w2) {
            double ov = sRedV[w2 * TB + t]; int oi = sRedI[w2 * TB + t];
            if (ov < v || (ov == v && oi < ix)) { v = ov; ix = oi; }
        }
        g_nnv[sIdx[t]] = v;
        g_nni[sIdx[t]] = ix;
    }
}

// ----------------------------------------------------------- merge_pass ----
// Merge ALL mutual pairs (disjoint => one thread owns one merge), then rebuild
// the compacted active list with an order-preserving block scan.
__global__ void __launch_bounds__(1024) merge_pass() {
    if (g_done) return;
    __shared__ int sWave[16];
    const int t = threadIdx.x, lane = t & 63, w = t >> 6;

    for (int b = t; b < NPTS; b += 1024) {
        int j = g_nni[b];
        if (j > b && j < NPTS && g_nni[j] == b) {   // mutual pair, b = keeper
            int r = atomicAdd(&g_mcount, 1);
            g_reci[r] = b; g_recj[r] = j; g_rech[r] = g_nnv[b];
            double sb = g_sz[b], sj = g_sz[j], s2 = sb + sj;
            double nr = 0.0;
            for (int d = 0; d < DIM; ++d) {
                double v = (sb * g_cent[d * PITCH + b] + sj * g_cent[d * PITCH + j]) / s2;
                g_cent[d * PITCH + b] = v;
                nr += v * v;
            }
            g_sz[b] = s2; g_nrm[b] = nr;
            g_act[j] = 0; g_nni[j] = -1; g_nnv[j] = (double)INFINITY;
        }
    }
    __syncthreads();

    // order-preserving compaction: thread t owns slots 2t, 2t+1
    int e0 = 2 * t, e1 = 2 * t + 1;
    int c0 = g_act[e0], c1 = g_act[e1];
    int sum = c0 + c1;
    int v = sum;                               // wave inclusive scan
    for (int off = 1; off < 64; off <<= 1) {
        int o = __shfl_up(v, off);
        if (lane >= off) v += o;
    }
    if (lane == 63) sWave[w] = v;
    __syncthreads();
    if (t == 0) {                              // exclusive scan of 16 wave sums
        int run = 0;
        for (int i = 0; i < 16; ++i) { int x = sWave[i]; sWave[i] = run; run += x; }
    }
    __syncthreads();
    int base = sWave[w] + (v - sum);           // exclusive prefix for this thread
    if (c0) g_cidx[base]      = e0;
    if (c1) g_cidx[base + c0] = e1;
    if (t == 1023) {
        int a2 = base + sum;                   // last thread's inclusive = total
        g_a = a2;
        g_done = (a2 <= 1) ? 1 : 0;
    }
}

// ------------------------------------------------------------- finisher ----
// (byte-identical logic to the R5-passing version)
__global__ void __launch_bounds__(1024) finisher(const int* __restrict__ kptr,
                                                 float* __restrict__ out) {
    __shared__ double D0[NPTS];   // 16 KB: nnv / sort keys
    __shared__ int    I0[NPTS];   //  8 KB: nni / sort payload
    __shared__ int    I1[NPTS];   //  8 KB: parent ping
    __shared__ int    I2[NPTS];   //  8 KB: parent pong
    __shared__ int    I3[NPTS];   //  8 KB: rank ping
    __shared__ int    I4[NPTS];   //  8 KB: rank pong
    __shared__ int    sNp;

    const int t = threadIdx.x, lane = t & 63, w = t >> 6;
    const int k = *kptr;
    int a = g_a;

    // ---- phase 2: in-block mutual-NN safety net until FULL dendrogram ----
    for (int guard = 0; guard < NPTS && a > 1; ++guard) {
        for (int b = w; b < NPTS; b += 16) {          // wave w owns slot b
            if (!g_act[b]) { if (lane == 0) { D0[b] = (double)INFINITY; I0[b] = -1; } continue; }
            double sb = g_sz[b], nb = g_nrm[b];
            double bvv = (double)INFINITY; int bii = 0x7FFFFFFF;
            for (int m = lane; m < NPTS; m += 64) {
                if (!g_act[m] || m == b) continue;
                double dot = 0.0;
                for (int d = 0; d < DIM; ++d)
                    dot += g_cent[d * PITCH + b] * g_cent[d * PITCH + m];
                double sm = g_sz[m], nm = g_nrm[m];
                double f = (sb * sm) / (sb + sm);
                double D = (2.0 * f) * ((nb + nm) - 2.0 * dot);
                if (D < bvv || (D == bvv && m < bii)) { bvv = D; bii = m; }
            }
            for (int off = 1; off < 64; off <<= 1) {
                double ov = __shfl_xor(bvv, off);
                int    oi = __shfl_xor(bii, off);
                if (ov < bvv || (ov == bvv && oi < bii)) { bvv = ov; bii = oi; }
            }
            if (lane == 0) { D0[b] = bvv; I0[b] = bii; }
        }
        __syncthreads();
        if (t == 0) sNp = 0;
        __syncthreads();
        for (int b = t; b < NPTS; b += 1024) {
            int j = I0[b];
            if (j > b && j < NPTS && I0[j] == b) {
                int r = atomicAdd(&g_mcount, 1);
                g_reci[r] = b; g_recj[r] = j; g_rech[r] = D0[b];
                double sb = g_sz[b], sj = g_sz[j], s2 = sb + sj;
                double nr = 0.0;
                for (int d = 0; d < DIM; ++d) {
                    double v = (sb * g_cent[d * PITCH + b] + sj * g_cent[d * PITCH + j]) / s2;
                    g_cent[d * PITCH + b] = v; nr += v * v;
                }
                g_sz[b] = s2; g_nrm[b] = nr; g_act[j] = 0;
                atomicAdd(&sNp, 1);
            }
        }
        __syncthreads();
        a -= sNp;
        __syncthreads();
    }

    // ---- phase 3: sort ALL heights, apply the n-k smallest, rank, scatter ----
    const int M    = g_mcount;
    const int nsel = NPTS - k;
    __syncthreads();
    for (int e = t; e < NPTS; e += 1024) {
        D0[e] = (e < M) ? g_rech[e] : (double)INFINITY;
        I0[e] = e;
    }
    __syncthreads();
    for (int k2 = 2; k2 <= NPTS; k2 <<= 1) {
        for (int j2 = k2 >> 1; j2 > 0; j2 >>= 1) {
            for (int i = t; i < NPTS; i += 1024) {
                int ixj = i ^ j2;
                if (ixj > i) {
                    bool up = ((i & k2) == 0);
                    double a0 = D0[i], a1 = D0[ixj];
                    if (up ? (a0 > a1) : (a0 < a1)) {
                        D0[i] = a1; D0[ixj] = a0;
                        int ti_ = I0[i]; I0[i] = I0[ixj]; I0[ixj] = ti_;
                    }
                }
            }
            __syncthreads();
        }
    }
    for (int p = t; p < NPTS; p += 1024) I1[p] = p;
    __syncthreads();
    for (int r = t; r < nsel; r += 1024) {
        int rec = I0[r];
        I1[g_recj[rec]] = g_reci[rec];   // each killed slot appears exactly once
    }
    __syncthreads();
    int* psrc = I1; int* pdst = I2;
    for (int it2 = 0; it2 < 11; ++it2) {          // 2^11 >= max chain depth
        for (int p = t; p < NPTS; p += 1024) pdst[p] = psrc[psrc[p]];
        __syncthreads();
        int* tp = psrc; psrc = pdst; pdst = tp;
    }
    for (int p = t; p < NPTS; p += 1024) I3[p] = (psrc[p] == p) ? 1 : 0;
    __syncthreads();
    int* rsrc = I3; int* rdst = I4;
    for (int off = 1; off < NPTS; off <<= 1) {
        for (int p = t; p < NPTS; p += 1024)
            rdst[p] = rsrc[p] + ((p >= off) ? rsrc[p - off] : 0);
        __syncthreads();
        int* tp = rsrc; rsrc = rdst; rdst = tp;
    }
    for (int p = t; p < NPTS; p += 1024) {
        int lbl = rsrc[psrc[p]] - 1;              // rank of root, ascending
        out[(size_t)p * k + lbl] = 1.0f;          // out pre-zeroed
    }
}

// -------------------------------------------------------------- launch ----
extern "C" void kernel_launch(void* const* d_in, const int* in_sizes, int n_in,
                              void* d_out, int out_size, void* d_ws, size_t ws_size,
                              hipStream_t stream) {
    const float* x    = (const float*)d_in[0];
    const int*   kptr = (const int*)d_in[1];
    float*       out  = (float*)d_out;

    hipMemsetAsync(d_out, 0, (size_t)out_size * sizeof(float), stream);
    init_kernel<<<8, 256, 0, stream>>>(x);
    for (int r = 0; r < ROUNDS; ++r) {
        nn_pass<<<NPTS / TB, 512, 0, stream>>>();
        merge_pass<<<1, 1024, 0, stream>>>();
    }
    finisher<<<1, 1024, 0, stream>>>(kptr, out);
}